// Round 17
// baseline (231.310 us; speedup 1.0000x reference)
//
#include <hip/hip_runtime.h>

// B=16, L=2048, K=24, D=64
typedef _Float16 f16;
typedef _Float16 f16x4 __attribute__((ext_vector_type(4)));
typedef _Float16 f16x8 __attribute__((ext_vector_type(8)));
typedef float f32x4 __attribute__((ext_vector_type(4)));

__device__ __forceinline__ void gl_lds16(const void* g, void* l) {
  __builtin_amdgcn_global_load_lds(
      (__attribute__((address_space(1))) unsigned int*)(g),
      (__attribute__((address_space(3))) unsigned int*)(l), 16, 0, 0);
}

// ---- k_pre0: ALL independent precompute in launch #1 (728 blocks).
//   blk 0..255:   uin — in (fp32) -> f16, pre-swizzled 8192-f16 planes
//   blk 256..279: phiT[k][e][d] = (f16) m_phi[(k*64+d)*64+e]
//   blk 280..663: Dpre phase-replicated Toeplitz tables
//   blk 664..727: zero out[]
__global__ __launch_bounds__(256) void k_pre0(const float* __restrict__ in,
                                              const float* __restrict__ m_phi,
                                              const float* __restrict__ ev,
                                              const float* __restrict__ evec,
                                              f16* __restrict__ phiT,
                                              f16* __restrict__ uin,
                                              f16* __restrict__ Dpre,
                                              float* __restrict__ out) {
  __shared__ float esm[256];
  int blk = blockIdx.x;
  int tid = threadIdx.x;
  if (blk < 256) {  // ---- uin conversion (one 128-s x 64-d plane per block)
    int b = blk >> 4, s0 = (blk & 15) * 128;
    f16* up = uin + (size_t)blk * 8192;
#pragma unroll
    for (int v = 0; v < 4; ++v) {
      int flat = v * 256 + tid;
      int row = flat >> 3, cl = flat & 7, cg = cl ^ (row & 7);
      const float* g = in + ((size_t)(b * 2048 + s0 + row)) * 64 + cg * 8;
      float4 u0 = *(const float4*)g;
      float4 u1 = *(const float4*)(g + 4);
      f16x8 h;
      h[0] = (f16)u0.x; h[1] = (f16)u0.y; h[2] = (f16)u0.z; h[3] = (f16)u0.w;
      h[4] = (f16)u1.x; h[5] = (f16)u1.y; h[6] = (f16)u1.z; h[7] = (f16)u1.w;
      *(f16x8*)&up[flat * 8] = h;
    }
    return;
  }
  if (blk < 280) {  // ---- phiT transpose
    int k = blk - 256;
    for (int idx = tid; idx < 4096; idx += 256) {
      int e = idx >> 6, d = idx & 63;
      phiT[k * 4096 + idx] = (f16)m_phi[(k * 64 + d) * 64 + e];
    }
    return;
  }
  if (blk < 664) {  // ---- Dpre blocks (384): D[p][y]=esm[254-p-y], pad 2560
    int a = blk - 280;
    int diag = a / 24, k = a % 24;
    float s4 = sqrtf(sqrtf(ev[k]));
    int base = diag * 128 - 127;
    if (tid < 255) {
      int v = base + tid;
      esm[tid] = (v >= 0) ? evec[v * 24 + k] * s4 : 0.0f;
    }
    __syncthreads();
    f16* plane = Dpre + (size_t)(diag * 24 + k) * 2560;
    for (int i = tid; i < 2560; i += 256) {
      float val = 0.f;
      if (i < 2112) {
        int p = i / 264, y = i - p * 264;
        int g = 254 - p - y;
        if (g >= 0) val = esm[g];
      }
      plane[i] = (f16)val;
    }
    return;
  }
  // ---- zero-out blocks: 64 blocks x 32768 floats
  float4* o = (float4*)(out + (size_t)(blk - 664) * 32768);
  float4 z4 = {0.f, 0.f, 0.f, 0.f};
#pragma unroll
  for (int i = 0; i < 32; ++i) o[i * 256 + tid] = z4;
}

// ---- k_main2: FULLY FUSED causal block-Toeplitz GEMM (R17).
// W2T is never materialized: each block computes its own B-tile on chip.
//   prologue: stage u planes (b0,b0+1 @ st-tile; 32KB, ONCE) + phiT(k=0)
//   per k:  W-GEMM (A=u s-rows, B=phiT e-rows; k_w's proven fragment scheme)
//           -> syncA -> stage Dsm(k), transpose-write accw into Bsm (R15
//           layout), prefetch phiT(k+1) -> syncB (13KB drain) ->
//           main-GEMM(k) (R15 body: Dsm phase table + Bsm bf reads).
// Deletes k_w (~55us) + 100MB W2T HBM writes + ~850MB L2 re-reads, at +50%
// MFMA (util was 36% -> headroom). LDS 77KB -> 2 blocks/CU.
__global__ __launch_bounds__(256, 2) void k_main2(const f16* __restrict__ Dpre,
                                                  const f16* __restrict__ phiT,
                                                  const f16* __restrict__ uin,
                                                  float* __restrict__ out) {
  __shared__ __align__(16) f16 Ubuf[2 * 8192];  // 32 KB (u, both b, staged once)
  __shared__ __align__(16) f16 Psm[4096];       // 8 KB  (phiT[k])
  __shared__ __align__(16) f16 Dsm[2560];       // 5 KB  (Toeplitz phase table)
  __shared__ __align__(16) f16 Bsm[16384];      // 32 KB (on-chip W tile)
  int nt = blockIdx.x;
  int q = blockIdx.y;
  int diag = 0, off = 0;
  while (off + (16 - diag) <= q) { off += 16 - diag; ++diag; }
  int st = q - off;
  int mt = st + diag;
  int tid = threadIdx.x, lane = tid & 63, wv = tid >> 6;
  int ml = lane & 15, qv = lane >> 4;
  // main-GEMM wave mapping (R15)
  int wm = (wv & 1) * 64, wn = (wv >> 1) * 64;
  int b0 = nt * 2;
  int p264 = (7 - (ml & 7)) * 264;
  int yb = (ml < 8 ? 120 : 112) - wm;
  // W-GEMM wave mapping: quarter = (bb, s-half)
  int bb = wv >> 1;
  int sh = (wv & 1) * 64;

  f32x4 zero = {0.f, 0.f, 0.f, 0.f};
  f32x4 acc[4][4];
#pragma unroll
  for (int x = 0; x < 4; ++x)
#pragma unroll
    for (int y = 0; y < 4; ++y) acc[x][y] = zero;

  // ---- prologue: stage u planes (pre-swizzled; contiguous gl_lds) + phiT(0)
  const f16* up0 = uin + (size_t)(b0 * 16 + st) * 8192;
  const f16* up1 = uin + (size_t)((b0 + 1) * 16 + st) * 8192;
#pragma unroll
  for (int v = 0; v < 4; ++v)
    gl_lds16(up0 + (size_t)(v * 256 + tid) * 8, &Ubuf[(v * 256 + wv * 64) * 8]);
#pragma unroll
  for (int v = 0; v < 4; ++v)
    gl_lds16(up1 + (size_t)(v * 256 + tid) * 8, &Ubuf[8192 + (v * 256 + wv * 64) * 8]);
#pragma unroll
  for (int v = 0; v < 2; ++v) {
    int flat = v * 256 + tid;
    int row = flat >> 3, cl = flat & 7, cg = cl ^ (row & 7);
    gl_lds16(phiT + row * 64 + cg * 8, &Psm[(v * 256 + wv * 64) * 8]);
  }
  __syncthreads();

  const f16* dplane = Dpre + (size_t)(diag * 24) * 2560;
  const f16* ub = Ubuf + bb * 8192;

  for (int k = 0; k < 24; ++k) {
    // ---- W-GEMM: accw[s-tile x][e-tile y] over K=64 d (2 ks of 32)
    f32x4 accw[4][4];
#pragma unroll
    for (int x = 0; x < 4; ++x)
#pragma unroll
      for (int y = 0; y < 4; ++y) accw[x][y] = zero;
#pragma unroll
    for (int ks = 0; ks < 2; ++ks) {
      f16x8 afw[4], bfw[4];
#pragma unroll
      for (int x = 0; x < 4; ++x) {
        int s = sh + x * 16 + ml;
        int ch = (ks * 4 + qv) ^ (s & 7);
        afw[x] = *(const f16x8*)&ub[s * 64 + ch * 8];
      }
#pragma unroll
      for (int y = 0; y < 4; ++y) {
        int e = y * 16 + ml;
        int ch = (ks * 4 + qv) ^ (e & 7);
        bfw[y] = *(const f16x8*)&Psm[e * 64 + ch * 8];
      }
#pragma unroll
      for (int x = 0; x < 4; ++x)
#pragma unroll
        for (int y = 0; y < 4; ++y)
          accw[x][y] = __builtin_amdgcn_mfma_f32_16x16x32_f16(afw[x], bfw[y], accw[x][y], 0, 0, 0);
    }
    __syncthreads();  // syncA: prev main-GEMM Bsm/Dsm reads + this W's Psm reads done
    // stage Dsm(k)
    const f16* dk = dplane + k * 2560;
    gl_lds16(dk + tid * 8, &Dsm[(wv * 64) * 8]);
    if (wv == 0) gl_lds16(dk + (256 + lane) * 8, &Dsm[2048]);
    // transpose-write accw -> Bsm (R15 layout: pos chunk p holds s-chunk p^(n&15))
#pragma unroll
    for (int x = 0; x < 4; ++x) {
      int s_loc = sh + x * 16 + qv * 4;
      int c = s_loc >> 3, so = s_loc & 7;
#pragma unroll
      for (int y = 0; y < 4; ++y) {
        int n = bb * 64 + y * 16 + ml;
        f16x4 pk;
        pk[0] = (f16)accw[x][y][0]; pk[1] = (f16)accw[x][y][1];
        pk[2] = (f16)accw[x][y][2]; pk[3] = (f16)accw[x][y][3];
        *(f16x4*)&Bsm[n * 128 + (c ^ (n & 15)) * 8 + so] = pk;
      }
    }
    // prefetch phiT(k+1)
    int kn = (k < 23) ? k + 1 : 23;
#pragma unroll
    for (int v = 0; v < 2; ++v) {
      int flat = v * 256 + tid;
      int row = flat >> 3, cl = flat & 7, cg = cl ^ (row & 7);
      gl_lds16(phiT + (size_t)kn * 4096 + row * 64 + cg * 8,
               &Psm[(v * 256 + wv * 64) * 8]);
    }
    __syncthreads();  // syncB: Bsm writes + Dsm(k) + Psm(k+1) drained
    // ---- main-GEMM(k): R15 body
#pragma unroll
    for (int ks = 0; ks < 4; ++ks) {
      int s0q = ks * 32 + qv * 8;
      f16x8 af[4], bf[4];
#pragma unroll
      for (int x = 0; x < 4; ++x)
        af[x] = *(const f16x8*)&Dsm[p264 + s0q - x * 16 + yb];
#pragma unroll
      for (int y = 0; y < 4; ++y) {
        int n = wn + y * 16 + ml;
        int cl = (ks * 4 + qv) ^ (n & 15);
        bf[y] = *(const f16x8*)&Bsm[n * 128 + cl * 8];
      }
#pragma unroll
      for (int x = 0; x < 4; ++x)
#pragma unroll
        for (int y = 0; y < 4; ++y)
          acc[x][y] = __builtin_amdgcn_mfma_f32_16x16x32_f16(af[x], bf[y], acc[x][y], 0, 0, 0);
    }
  }
  int t0 = mt * 128 + wm;
  int n0 = nt * 128 + wn;
#pragma unroll
  for (int x = 0; x < 4; ++x) {
    int rbase = t0 + x * 16 + (qv << 2);
#pragma unroll
    for (int y = 0; y < 4; ++y) {
      int col = n0 + y * 16 + ml;
      int b = col >> 6, e = col & 63;
#pragma unroll
      for (int r = 0; r < 4; ++r)
        atomicAdd(&out[((size_t)(b * 2048 + rbase + r)) * 64 + e], acc[x][y][r]);
    }
  }
}

extern "C" void kernel_launch(void* const* d_in, const int* in_sizes, int n_in,
                              void* d_out, int out_size, void* d_ws, size_t ws_size,
                              hipStream_t stream) {
  const float* inputs = (const float*)d_in[0];  // [16,2048,64]
  const float* m_phi = (const float*)d_in[1];   // [1536,64]
  const float* ev = (const float*)d_in[2];      // [24]
  const float* evec = (const float*)d_in[3];    // [2048,24]
  float* out = (float*)d_out;                   // [16,2048,64] fp32
  char* ws = (char*)d_ws;
  // ws layout: Dpre 1,966,080 | phiT 196,608 | uin 4,194,304  (W2T deleted)
  f16* Dpre = (f16*)(ws);
  f16* phiT = (f16*)(ws + 1966080);
  f16* uin = (f16*)(ws + 2162688);

  hipLaunchKernelGGL(k_pre0, dim3(728), dim3(256), 0, stream,
                     inputs, m_phi, ev, evec, phiT, uin, Dpre, out);
  hipLaunchKernelGGL(k_main2, dim3(8, 136), dim3(256), 0, stream,
                     Dpre, phiT, uin, out);
}